// Round 4
// baseline (456.995 us; speedup 1.0000x reference)
//
#include <hip/hip_runtime.h>

// m_btabl — round 4: single persistent kernel, barrier-free wave workers.
//
// Grid: 768 blocks x 256 thr (4 waves) = 3072 wave-workers, exactly 3 blocks/CU
// resident (LDS ~49.4 KB). Block prologue (once): max_norm + pack weights into
// LDS (redundant per block, ~2us). Then each wave loops over groups of 16
// samples (stride 3072), fully wave-local: no __syncthreads after prologue.
//
// Per group (wave-private):
//   stage1: lane (sLoc=lane>>2, c=lane&3) loads its sample's rows 10c..10c+9
//           (25 float4), computes Z = x@W2s -> bf16 -> sZ[wave] in B-operand
//           layout [col=5*sLoc+t][k=d]. Bias fold: one-hot rows k=40+t written
//           ONCE before the loop (static).
//   stage2: 5 n-tiles (80 cols), M=128 (8 m-tiles), K=48 via 2 MFMAs
//           (16x16x32 bf16); frag1 quads>=2 zeroed (k>=48 pad). Epilogue:
//           h=relu(acc), X3 += w1b*h in C-layout; quad-reduce via shfl.
//   stage3: lanes 0..15: per-sample attention + double softmax -> out.

typedef short bf16x8 __attribute__((ext_vector_type(8)));
typedef float f32x4v __attribute__((ext_vector_type(4)));

#define NT   256
#define WPB  4
#define GRID 768

__device__ __forceinline__ unsigned short f2bf(float f) {
    unsigned int u = __float_as_uint(f);
    u += 0x7FFFu + ((u >> 16) & 1u);   // round-to-nearest-even
    return (unsigned short)(u >> 16);
}

__device__ __forceinline__ float block_reduce_sum(float v, float* red, int tid) {
    #pragma unroll
    for (int off = 32; off > 0; off >>= 1) v += __shfl_xor(v, off, 64);
    if ((tid & 63) == 0) red[tid >> 6] = v;
    __syncthreads();
    float r = red[0] + red[1] + red[2] + red[3];
    __syncthreads();
    return r;
}

__global__ __launch_bounds__(NT)
void btabl_fused(const float* __restrict__ x,  const float* __restrict__ W1,
                 const float* __restrict__ W2, const float* __restrict__ B,
                 const float* __restrict__ Tw1,const float* __restrict__ Tw,
                 const float* __restrict__ Tw2,const float* __restrict__ TB,
                 const float* __restrict__ l,  float* __restrict__ out,
                 int nsamp)
{
    // A-row e: k<40 W1s | 40..44 bias | 45..47 zero; rows 120..127 + pad zero.
    __align__(16) __shared__ unsigned short sW1[128*48 + 16];   // 12320 B
    __align__(16) __shared__ float          sWp[128*4];         //  2048 B
    __align__(16) __shared__ float          sW2[52];            //   208 B
    __align__(16) __shared__ float          sC[36];             //   144 B
    __align__(16) __shared__ unsigned short sZ[WPB][80*48+16];  // 30848 B
    __align__(16) __shared__ float          sX3[WPB][80*3];     //  3840 B
    __shared__ float red[4];

    const int tid = threadIdx.x;

    // ---------------- prologue: norms + pack (per block, once) ----------------
    float ss;
    ss = 0.f; for (int i = tid; i < 4800; i += NT) { float w = W1[i];  ss += w*w; }
    const float n1 = sqrtf(block_reduce_sum(ss, red, tid));
    ss = 0.f; for (int i = tid; i < 50;   i += NT) { float w = W2[i];  ss += w*w; }
    const float n2 = sqrtf(block_reduce_sum(ss, red, tid));
    ss = 0.f; for (int i = tid; i < 360;  i += NT) { float w = Tw1[i]; ss += w*w; }
    const float n3 = sqrtf(block_reduce_sum(ss, red, tid));
    ss = 0.f; for (int i = tid; i < 25;   i += NT) { float w = Tw[i];  ss += w*w; }
    const float n4 = sqrtf(block_reduce_sum(ss, red, tid));
    ss = 0.f; for (int i = tid; i < 5;    i += NT) { float w = Tw2[i]; ss += w*w; }
    const float n5 = sqrtf(block_reduce_sum(ss, red, tid));

    const float s1 = n1 > 10.f ? 10.f/(1e-8f+n1) : 1.f;
    const float s2 = n2 > 10.f ? 10.f/(1e-8f+n2) : 1.f;
    const float s3 = n3 > 10.f ? 10.f/(1e-8f+n3) : 1.f;
    const float s4 = n4 > 10.f ? 10.f/(1e-8f+n4) : 1.f;
    const float s5 = n5 > 10.f ? 10.f/(1e-8f+n5) : 1.f;

    for (int i = tid; i < 128*48+16; i += NT) {
        const int e = i / 48, k = i - e*48;
        float v = 0.f;
        if (e < 120) {
            if (k < 40)      v = W1[e*40 + k] * s1;
            else if (k < 45) v = B[e*5 + (k-40)];
        }
        sW1[i] = f2bf(v);
    }
    for (int i = tid; i < 512; i += NT) {
        const int e = i >> 2, c = i & 3;
        sWp[i] = (c < 3 && e < 120) ? Tw1[c*120 + e] * s3 : 0.f;
    }
    for (int i = tid; i < 52; i += NT) sW2[i] = (i < 50) ? W2[i]*s2 : 0.f;
    for (int i = tid; i < 36; i += NT) {
        float v = 0.f;
        if (i < 25)      { int r = i/5, c = i - r*5; v = (r == c) ? 0.2f : Tw[i]*s4; }
        else if (i < 30) v = Tw2[i-25] * s5;
        else if (i < 33) v = TB[i-30];
        else if (i == 33){ float lv = l[0]; v = fminf(fmaxf(lv, 0.f), 1.f); }
        sC[i] = v;
    }
    __syncthreads();   // last barrier in the kernel

    const int wv   = tid >> 6;
    const int lane = tid & 63;
    const int quad = lane >> 4;
    const int m    = lane & 15;
    const int sLoc = lane >> 2;
    const int cc   = lane & 3;

    unsigned short* zp  = &sZ[wv][0];
    float*          x3p = &sX3[wv][0];

    // static bias one-hot rows (k=40..47) for this wave's 80 cols — write once
    {
        unsigned int* z32 = (unsigned int*)zp;
        for (int col = lane; col < 80; col += 64) {
            const int t = col % 5;
            const int base = col*24 + 20;          // dword index of k=40
            #pragma unroll
            for (int j = 0; j < 4; j++) z32[base + j] = 0u;
            z32[base + (t >> 1)] = (t & 1) ? 0x3F800000u : 0x00003F80u;
        }
    }

    const int ngroups = (nsamp + 15) >> 4;
    const int wid     = blockIdx.x * WPB + wv;
    const float lam   = sC[33];
    const float olam  = 1.f - lam;

    for (int g = wid; g < ngroups; g += GRID*WPB) {
        // ---- stage 1: Z = x@W2s -> bf16 -> sZ (wave-local) ----
        {
            const int sG  = g*16 + sLoc;
            const int sCl = sG < nsamp ? sG : nsamp - 1;
            const float* xs = x + (size_t)sCl*400 + cc*100;   // 10 rows of 10

            float w2l[50];
            #pragma unroll
            for (int i = 0; i < 50; i++) w2l[i] = sW2[i];

            const int colB = sLoc * 5;
            #pragma unroll
            for (int pr = 0; pr < 5; pr++) {                  // rows 2pr, 2pr+1
                const float4* xv = (const float4*)(xs + pr*20);
                float4 a0 = xv[0], a1 = xv[1], a2 = xv[2], a3 = xv[3], a4 = xv[4];
                const float v[20] = {a0.x,a0.y,a0.z,a0.w, a1.x,a1.y,a1.z,a1.w,
                                     a2.x,a2.y,a2.z,a2.w, a3.x,a3.y,a3.z,a3.w,
                                     a4.x,a4.y,a4.z,a4.w};
                #pragma unroll
                for (int t = 0; t < 5; t++) {
                    float z0 = 0.f, z1 = 0.f;
                    #pragma unroll
                    for (int k = 0; k < 10; k++) {
                        z0 = fmaf(v[k],      w2l[k*5+t], z0);
                        z1 = fmaf(v[10+k],   w2l[k*5+t], z1);
                    }
                    const unsigned int dw =
                        (unsigned int)f2bf(z0) | ((unsigned int)f2bf(z1) << 16);
                    *(unsigned int*)(zp + (colB + t)*48 + cc*10 + pr*2) = dw;
                }
            }
        }

        // ---- stage 2: MFMA GEMM + X3 epilogue (wave-local; lgkm waits only) ----
        bf16x8 Bf0[5], Bf1[5];
        const bf16x8 z8 = {0,0,0,0,0,0,0,0};
        #pragma unroll
        for (int nt = 0; nt < 5; nt++) {
            const unsigned short* bcol = zp + (nt*16 + m)*48;
            Bf0[nt] = *(const bf16x8*)(bcol + quad*8);
            bf16x8 b1 = *(const bf16x8*)(bcol + 32 + quad*8);
            Bf1[nt] = (quad >= 2) ? z8 : b1;                  // k>=48 pad
        }

        float X3p[5][3];
        #pragma unroll
        for (int nt = 0; nt < 5; nt++)
            #pragma unroll
            for (int j = 0; j < 3; j++) X3p[nt][j] = 0.f;

        const f32x4v zac = {0.f,0.f,0.f,0.f};
        #pragma unroll
        for (int mt = 0; mt < 8; mt++) {
            const unsigned short* ar = sW1 + (mt*16 + m)*48;
            const bf16x8 A0 = *(const bf16x8*)(ar + quad*8);
            const bf16x8 A1 = *(const bf16x8*)(ar + 32 + quad*8);  // finite pad
            f32x4v wp[4];
            #pragma unroll
            for (int r = 0; r < 4; r++)
                wp[r] = *(const f32x4v*)(sWp + (mt*16 + quad*4 + r)*4);
            #pragma unroll
            for (int nt = 0; nt < 5; nt++) {
                f32x4v acc = __builtin_amdgcn_mfma_f32_16x16x32_bf16(A0, Bf0[nt], zac, 0,0,0);
                acc = __builtin_amdgcn_mfma_f32_16x16x32_bf16(A1, Bf1[nt], acc, 0,0,0);
                #pragma unroll
                for (int r = 0; r < 4; r++) {
                    const float h = fmaxf(acc[r], 0.f);
                    X3p[nt][0] = fmaf(wp[r][0], h, X3p[nt][0]);
                    X3p[nt][1] = fmaf(wp[r][1], h, X3p[nt][1]);
                    X3p[nt][2] = fmaf(wp[r][2], h, X3p[nt][2]);
                }
            }
        }

        #pragma unroll
        for (int nt = 0; nt < 5; nt++) {
            #pragma unroll
            for (int j = 0; j < 3; j++) {
                float v = X3p[nt][j];
                v += __shfl_xor(v, 16, 64);
                v += __shfl_xor(v, 32, 64);
                if (quad == 0) x3p[(nt*16 + m)*3 + j] = v;
            }
        }

        // ---- stage 3: per-sample attention tail (lanes 0..15) ----
        if (lane < 16) {
            float X3v[3][5];
            #pragma unroll
            for (int t = 0; t < 5; t++)
                #pragma unroll
                for (int j = 0; j < 3; j++)
                    X3v[j][t] = x3p[(lane*5 + t)*3 + j];

            float y[3];
            #pragma unroll
            for (int j = 0; j < 3; j++) {
                float S[5];
                #pragma unroll
                for (int t = 0; t < 5; t++) {
                    float a = 0.f;
                    #pragma unroll
                    for (int k = 0; k < 5; k++)
                        a = fmaf(X3v[j][k], sC[k*5 + t], a);
                    S[t] = a;
                }
                float mx = S[0];
                #pragma unroll
                for (int t = 1; t < 5; t++) mx = fmaxf(mx, S[t]);
                float ex[5], se = 0.f;
                #pragma unroll
                for (int t = 0; t < 5; t++) { ex[t] = __expf(S[t]-mx); se += ex[t]; }
                const float inv = 1.f / se;
                float yj = sC[30 + j];
                #pragma unroll
                for (int t = 0; t < 5; t++) {
                    const float a  = ex[t] * inv;
                    const float xc = X3v[j][t] * (lam + olam * a);
                    yj = fmaf(xc, sC[25 + t], yj);
                }
                y[j] = yj;
            }
            const float mx = fmaxf(y[0], fmaxf(y[1], y[2]));
            const float e0 = __expf(y[0]-mx), e1 = __expf(y[1]-mx), e2 = __expf(y[2]-mx);
            const float inv = 1.f / (e0 + e1 + e2);
            const int sG = g*16 + lane;
            if (sG < nsamp) {
                float* o = out + (size_t)sG*3;
                o[0] = e0*inv; o[1] = e1*inv; o[2] = e2*inv;
            }
        }
    }
}

extern "C" void kernel_launch(void* const* d_in, const int* in_sizes, int n_in,
                              void* d_out, int out_size, void* d_ws, size_t ws_size,
                              hipStream_t stream) {
    const float* x   = (const float*)d_in[0];
    const float* W1  = (const float*)d_in[1];
    const float* W2  = (const float*)d_in[2];
    const float* B   = (const float*)d_in[3];
    const float* Tw1 = (const float*)d_in[4];
    const float* Tw  = (const float*)d_in[5];
    const float* Tw2 = (const float*)d_in[6];
    const float* TB  = (const float*)d_in[7];
    const float* l   = (const float*)d_in[8];
    float* out = (float*)d_out;

    const int nsamp = in_sizes[0] / 400;
    hipLaunchKernelGGL(btabl_fused, dim3(GRID), dim3(NT), 0, stream,
                       x, W1, W2, B, Tw1, Tw, Tw2, TB, l, out, nsamp);
}

// Round 5
// 392.782 us; speedup vs baseline: 1.1635x; 1.1635x over previous
//
#include <hip/hip_runtime.h>

// m_btabl — round 5: persistent barrier-free wave workers, spill-free.
//
// prep_kernel (1 block): max_norm + pack into d_ws (floats):
//   [0,3096)     W1 image bf16 ushort[129*48]: e<120: k<40 W1s | 40..44 bias | pad 0
//   [3096,3608)  w1b pack f32 [128][4] = {w1b0,w1b1,w1b2,0}
//   [3608,3644)  consts: Wm(25, diag=0.2) | W2b(5) | TB(3) | lam | pad
//   [3644,3694)  W2s (50)
//
// btabl_main: 768 blocks x 256 thr (4 waves) = 3072 persistent wave-workers,
// 3 blocks/CU (LDS 48.0 KB). Prologue: float4-copy W1 image + Wp to LDS.
// Consts/W2 read via uniform ws pointers -> s_load/SGPR (no VGPR cost).
// Group loop (16 samples/wave/iter, stride 3072), wave-local, no barriers:
//   stage1: lane (sLoc=lane>>2, cc=lane&3) computes 10 rows of Z=x@W2s -> bf16
//           -> sZ[wave] B-layout [col=5*sLoc+t][k]; one-hot bias rows written once.
//   stage2: 5 n-tiles x 8 m-tiles, K=48 via 2 MFMAs (16x16x32 bf16);
//           A/Wp LDS reads use asm-opaqued indices so they can't be hoisted
//           into VGPRs across the group loop (round-4 spill cause).
//   stage3: lanes 0..15: per-sample attention + double softmax -> out.

typedef short bf16x8 __attribute__((ext_vector_type(8)));
typedef float f32x4v __attribute__((ext_vector_type(4)));

#define NT   256
#define WPB  4
#define GRID 768

__device__ __forceinline__ unsigned short f2bf(float f) {
    unsigned int u = __float_as_uint(f);
    u += 0x7FFFu + ((u >> 16) & 1u);   // round-to-nearest-even
    return (unsigned short)(u >> 16);
}

// ---------------- prep kernel ----------------
__device__ __forceinline__ float block_reduce_sum(float v, float* red, int tid) {
    #pragma unroll
    for (int off = 32; off > 0; off >>= 1) v += __shfl_xor(v, off, 64);
    if ((tid & 63) == 0) red[tid >> 6] = v;
    __syncthreads();
    float r = red[0] + red[1] + red[2] + red[3];
    __syncthreads();
    return r;
}

__global__ __launch_bounds__(NT)
void prep_kernel(const float* __restrict__ W1, const float* __restrict__ W2,
                 const float* __restrict__ B,  const float* __restrict__ Tw1,
                 const float* __restrict__ Tw, const float* __restrict__ Tw2,
                 const float* __restrict__ TB, const float* __restrict__ l,
                 float* __restrict__ ws)
{
    __shared__ float red[4];
    const int tid = threadIdx.x;
    float ss;
    ss = 0.f; for (int i = tid; i < 4800; i += NT) { float w = W1[i];  ss += w*w; }
    const float n1 = sqrtf(block_reduce_sum(ss, red, tid));
    ss = 0.f; for (int i = tid; i < 50;   i += NT) { float w = W2[i];  ss += w*w; }
    const float n2 = sqrtf(block_reduce_sum(ss, red, tid));
    ss = 0.f; for (int i = tid; i < 360;  i += NT) { float w = Tw1[i]; ss += w*w; }
    const float n3 = sqrtf(block_reduce_sum(ss, red, tid));
    ss = 0.f; for (int i = tid; i < 25;   i += NT) { float w = Tw[i];  ss += w*w; }
    const float n4 = sqrtf(block_reduce_sum(ss, red, tid));
    ss = 0.f; for (int i = tid; i < 5;    i += NT) { float w = Tw2[i]; ss += w*w; }
    const float n5 = sqrtf(block_reduce_sum(ss, red, tid));

    const float s1 = n1 > 10.f ? 10.f/(1e-8f+n1) : 1.f;
    const float s2 = n2 > 10.f ? 10.f/(1e-8f+n2) : 1.f;
    const float s3 = n3 > 10.f ? 10.f/(1e-8f+n3) : 1.f;
    const float s4 = n4 > 10.f ? 10.f/(1e-8f+n4) : 1.f;
    const float s5 = n5 > 10.f ? 10.f/(1e-8f+n5) : 1.f;

    unsigned short* img = (unsigned short*)ws;
    for (int i = tid; i < 129*48; i += NT) {
        const int e = i / 48, k = i - e*48;
        float v = 0.f;
        if (e < 120) {
            if (k < 40)      v = W1[e*40 + k] * s1;
            else if (k < 45) v = B[e*5 + (k-40)];
        }
        img[i] = f2bf(v);
    }
    for (int i = tid; i < 512; i += NT) {
        const int e = i >> 2, c = i & 3;
        ws[3096 + i] = (c < 3 && e < 120) ? Tw1[c*120 + e] * s3 : 0.f;
    }
    for (int i = tid; i < 36; i += NT) {
        float v = 0.f;
        if (i < 25)      { int r = i/5, c = i - r*5; v = (r == c) ? 0.2f : Tw[i]*s4; }
        else if (i < 30) v = Tw2[i-25] * s5;
        else if (i < 33) v = TB[i-30];
        else if (i == 33){ float lv = l[0]; v = fminf(fmaxf(lv, 0.f), 1.f); }
        ws[3608 + i] = v;
    }
    for (int i = tid; i < 50; i += NT) ws[3644 + i] = W2[i] * s2;
}

// ---------------- main kernel ----------------
__global__ __launch_bounds__(NT)
void btabl_main(const float* __restrict__ x, const float* __restrict__ ws,
                float* __restrict__ out, int nsamp)
{
    __align__(16) __shared__ unsigned short sW1[129*48];        // 12384 B
    __align__(16) __shared__ float          sWp[128*4];         //  2048 B
    __align__(16) __shared__ unsigned short sZ[WPB][80*48+16];  // 30848 B
    __align__(16) __shared__ float          sX3[WPB][80*3];     //  3840 B
                                                                // = 49120 B -> 3 blk/CU

    const int tid = threadIdx.x;
    {   // prologue: stage packed weights (no norms here)
        const float4* src = (const float4*)ws;
        float4* d1 = (float4*)sW1;
        for (int i = tid; i < 774; i += NT) d1[i] = src[i];
        float4* d2 = (float4*)sWp;
        for (int i = tid; i < 128; i += NT) d2[i] = src[774 + i];
    }
    __syncthreads();   // last barrier

    const int wv   = tid >> 6;
    const int lane = tid & 63;
    const int quad = lane >> 4;
    const int m    = lane & 15;
    const int sLoc = lane >> 2;
    const int cc   = lane & 3;

    unsigned short* zp  = &sZ[wv][0];
    float*          x3p = &sX3[wv][0];

    // wave-uniform const pointers -> s_load / SGPR, zero VGPR cost
    const float* W2p = ws + 3644;
    const float* Cp  = ws + 3608;

    // static bias one-hot rows (k=40..47) for this wave's 80 cols — write once
    {
        unsigned int* z32 = (unsigned int*)zp;
        for (int col = lane; col < 80; col += 64) {
            const int t = col % 5;
            const int base = col*24 + 20;
            #pragma unroll
            for (int j = 0; j < 4; j++) z32[base + j] = 0u;
            z32[base + (t >> 1)] = (t & 1) ? 0x3F800000u : 0x00003F80u;
        }
    }

    const int ngroups = (nsamp + 15) >> 4;
    const int wid     = blockIdx.x * WPB + wv;
    const float lam   = Cp[33];
    const float olam  = 1.f - lam;

    // loop-opaque LDS indices: block cross-iteration promotion of A/Wp loads
    int aIdx  = m * 48;        // ushort idx into sW1 (lane A-row base)
    int wpIdx = quad * 16;     // float  idx into sWp (lane wp base)

    #pragma clang loop unroll(disable)
    for (int g = wid; g < ngroups; g += GRID*WPB) {
        asm volatile("" : "+v"(aIdx), "+v"(wpIdx));

        // ---- stage 1: Z = x@W2s -> bf16 -> sZ (wave-local) ----
        {
            const int sG  = g*16 + sLoc;
            const int sCl = sG < nsamp ? sG : nsamp - 1;
            const float* xs = x + (size_t)sCl*400 + cc*100;   // 10 rows of 10

            const int colB = sLoc * 5;
            #pragma unroll
            for (int pr = 0; pr < 5; pr++) {                  // rows 2pr, 2pr+1
                const float4* xv = (const float4*)(xs + pr*20);
                float4 a0 = xv[0], a1 = xv[1], a2 = xv[2], a3 = xv[3], a4 = xv[4];
                const float v[20] = {a0.x,a0.y,a0.z,a0.w, a1.x,a1.y,a1.z,a1.w,
                                     a2.x,a2.y,a2.z,a2.w, a3.x,a3.y,a3.z,a3.w,
                                     a4.x,a4.y,a4.z,a4.w};
                #pragma unroll
                for (int t = 0; t < 5; t++) {
                    float z0 = 0.f, z1 = 0.f;
                    #pragma unroll
                    for (int k = 0; k < 10; k++) {
                        const float w = W2p[k*5 + t];         // SGPR
                        z0 = fmaf(v[k],    w, z0);
                        z1 = fmaf(v[10+k], w, z1);
                    }
                    const unsigned int dw =
                        (unsigned int)f2bf(z0) | ((unsigned int)f2bf(z1) << 16);
                    *(unsigned int*)(zp + (colB + t)*48 + cc*10 + pr*2) = dw;
                }
            }
        }

        // ---- stage 2: MFMA GEMM + X3 epilogue (wave-local) ----
        bf16x8 Bf0[5], Bf1[5];
        const bf16x8 z8 = {0,0,0,0,0,0,0,0};
        #pragma unroll
        for (int nt = 0; nt < 5; nt++) {
            const unsigned short* bcol = zp + (nt*16 + m)*48;
            Bf0[nt] = *(const bf16x8*)(bcol + quad*8);
            bf16x8 b1 = *(const bf16x8*)(bcol + 32 + quad*8);
            Bf1[nt] = (quad >= 2) ? z8 : b1;                  // k>=48 pad
        }

        float X3p[5][3];
        #pragma unroll
        for (int nt = 0; nt < 5; nt++)
            #pragma unroll
            for (int j = 0; j < 3; j++) X3p[nt][j] = 0.f;

        const f32x4v zac = {0.f,0.f,0.f,0.f};
        #pragma unroll
        for (int mt = 0; mt < 8; mt++) {
            const bf16x8 A0 = *(const bf16x8*)(sW1 + aIdx + mt*768 + quad*8);
            const bf16x8 A1 = *(const bf16x8*)(sW1 + aIdx + mt*768 + 32 + quad*8);
            f32x4v wp[4];
            #pragma unroll
            for (int r = 0; r < 4; r++)
                wp[r] = *(const f32x4v*)(sWp + wpIdx + mt*64 + r*4);
            #pragma unroll
            for (int nt = 0; nt < 5; nt++) {
                f32x4v acc = __builtin_amdgcn_mfma_f32_16x16x32_bf16(A0, Bf0[nt], zac, 0,0,0);
                acc = __builtin_amdgcn_mfma_f32_16x16x32_bf16(A1, Bf1[nt], acc, 0,0,0);
                #pragma unroll
                for (int r = 0; r < 4; r++) {
                    const float h = fmaxf(acc[r], 0.f);
                    X3p[nt][0] = fmaf(wp[r][0], h, X3p[nt][0]);
                    X3p[nt][1] = fmaf(wp[r][1], h, X3p[nt][1]);
                    X3p[nt][2] = fmaf(wp[r][2], h, X3p[nt][2]);
                }
            }
        }

        #pragma unroll
        for (int nt = 0; nt < 5; nt++) {
            #pragma unroll
            for (int j = 0; j < 3; j++) {
                float v = X3p[nt][j];
                v += __shfl_xor(v, 16, 64);
                v += __shfl_xor(v, 32, 64);
                if (quad == 0) x3p[(nt*16 + m)*3 + j] = v;
            }
        }

        // ---- stage 3: per-sample attention tail (lanes 0..15) ----
        if (lane < 16) {
            float X3v[3][5];
            #pragma unroll
            for (int t = 0; t < 5; t++)
                #pragma unroll
                for (int j = 0; j < 3; j++)
                    X3v[j][t] = x3p[(lane*5 + t)*3 + j];

            float y[3];
            #pragma unroll
            for (int j = 0; j < 3; j++) {
                float S[5];
                #pragma unroll
                for (int t = 0; t < 5; t++) {
                    float a = 0.f;
                    #pragma unroll
                    for (int k = 0; k < 5; k++)
                        a = fmaf(X3v[j][k], Cp[k*5 + t], a);
                    S[t] = a;
                }
                float mx = S[0];
                #pragma unroll
                for (int t = 1; t < 5; t++) mx = fmaxf(mx, S[t]);
                float ex[5], se = 0.f;
                #pragma unroll
                for (int t = 0; t < 5; t++) { ex[t] = __expf(S[t]-mx); se += ex[t]; }
                const float inv = 1.f / se;
                float yj = Cp[30 + j];
                #pragma unroll
                for (int t = 0; t < 5; t++) {
                    const float a  = ex[t] * inv;
                    const float xc = X3v[j][t] * (lam + olam * a);
                    yj = fmaf(xc, Cp[25 + t], yj);
                }
                y[j] = yj;
            }
            const float mx = fmaxf(y[0], fmaxf(y[1], y[2]));
            const float e0 = __expf(y[0]-mx), e1 = __expf(y[1]-mx), e2 = __expf(y[2]-mx);
            const float inv = 1.f / (e0 + e1 + e2);
            const int sG = g*16 + lane;
            if (sG < nsamp) {
                float* o = out + (size_t)sG*3;
                o[0] = e0*inv; o[1] = e1*inv; o[2] = e2*inv;
            }
        }
    }
}

extern "C" void kernel_launch(void* const* d_in, const int* in_sizes, int n_in,
                              void* d_out, int out_size, void* d_ws, size_t ws_size,
                              hipStream_t stream) {
    const float* x   = (const float*)d_in[0];
    const float* W1  = (const float*)d_in[1];
    const float* W2  = (const float*)d_in[2];
    const float* B   = (const float*)d_in[3];
    const float* Tw1 = (const float*)d_in[4];
    const float* Tw  = (const float*)d_in[5];
    const float* Tw2 = (const float*)d_in[6];
    const float* TB  = (const float*)d_in[7];
    const float* l   = (const float*)d_in[8];
    float* out = (float*)d_out;
    float* ws  = (float*)d_ws;

    hipLaunchKernelGGL(prep_kernel, dim3(1), dim3(NT), 0, stream,
                       W1, W2, B, Tw1, Tw, Tw2, TB, l, ws);

    const int nsamp = in_sizes[0] / 400;
    hipLaunchKernelGGL(btabl_main, dim3(GRID), dim3(NT), 0, stream,
                       x, ws, out, nsamp);
}